// Round 1
// baseline (962.918 us; speedup 1.0000x reference)
//
#include <hip/hip_runtime.h>

// SetEncoderPointNet fused kernel, fp32 baseline.
//
// Shapes: x (8,256,256,64) f32; w1 (256,64); b1 (256); w2 (256,320); out (8,256,256,256).
// Restructure: out = x @ w2[:, :64]^T + v,  v[bn] = (max_m(x@w1^T) + b1) @ w2[:, 64:]^T.
// One block per (b,n) group: stage x-tile in LDS once, do both GEMMs + max + v fused.

#define MM   256
#define CIN  64
#define CMID 256
#define COUT 256

// workspace float layout
#define W1T_OFF   0        // [64][256]   w1t[k][d]  = w1[d][k]
#define W2XT_OFF  16384    // [64][256]   w2xt[k][j] = w2[j][k]
#define W2ZT_OFF  32768    // [256][256]  w2zt[d][j] = w2[j][64+d]
#define WS_FLOATS 98304    // 384 KB

__global__ void prep_transpose(const float* __restrict__ w1,
                               const float* __restrict__ w2,
                               float* __restrict__ ws) {
    int i = blockIdx.x * 256 + threadIdx.x;
    if (i < 16384) {
        int k = i >> 8, d = i & 255;
        ws[W1T_OFF + i] = w1[d * CIN + k];
    } else if (i < 32768) {
        int q = i - 16384;
        int k = q >> 8, j = q & 255;
        ws[W2XT_OFF + q] = w2[j * 320 + k];
    } else if (i < WS_FLOATS) {
        int q = i - 32768;
        int d = q >> 8, j = q & 255;
        ws[W2ZT_OFF + q] = w2[j * 320 + 64 + d];
    }
}

// 138 KB LDS -> 1 block/CU (of 160 KB). __launch_bounds__(256,1): 1 wave/EU min,
// VGPR budget up to 512 so the 8x8 register tile + unroll-2 operand regs fit.
__global__ __launch_bounds__(256, 1)
void fused_pointnet(const float* __restrict__ x,
                    const float* __restrict__ b1,
                    const float* __restrict__ ws,
                    float* __restrict__ out) {
    __shared__ float xs[MM * CIN];       // 64 KB  x tile, [m][k]
    __shared__ float wsh[CIN * CMID];    // 64 KB  weight tile, [k][d] (w1t, then w2xt)
    __shared__ float red[8 * 256];       // 8 KB   cross-mg reduction buffer
    __shared__ float zv[256];            // zmax + b1 per d
    __shared__ float vv[256];            // v[j] = zv . w2zt[:,j]

    const int tid = threadIdx.x;
    const int bn  = blockIdx.x;
    const float* __restrict__ xg = x + (size_t)bn * (MM * CIN);

    // ---- stage x tile (16384 floats) and w1t (16384 floats), float4-coalesced ----
    {
        const float4* xg4 = (const float4*)xg;
        float4* xs4 = (float4*)xs;
        const float4* wg4 = (const float4*)(ws + W1T_OFF);
        float4* wt4 = (float4*)wsh;
#pragma unroll
        for (int i = 0; i < 16; ++i) xs4[tid + 256 * i] = xg4[tid + 256 * i];
#pragma unroll
        for (int i = 0; i < 16; ++i) wt4[tid + 256 * i] = wg4[tid + 256 * i];
    }
    __syncthreads();

    // thread tiling: dg in [0,32) -> d quads {4*dg, 128+4*dg}; mg in [0,8) -> 8 m's per chunk.
    // lanes 0..31 of a wave share mg => x LDS reads are half-wave broadcasts (free);
    // w LDS reads are consecutive float4 across lanes (optimal pattern).
    const int dg = tid & 31;
    const int mg = tid >> 5;
    const int d0 = dg * 4;

    float vmax[8];
#pragma unroll
    for (int c = 0; c < 8; ++c) vmax[c] = -3.0e38f;

    // =================== phase 1: z = x@w1^T, running max over m ===================
    for (int chunk = 0; chunk < 4; ++chunk) {
        const int mbase = chunk * 64 + mg * 8;
        float acc[8][8];
#pragma unroll
        for (int r = 0; r < 8; ++r)
#pragma unroll
            for (int c = 0; c < 8; ++c) acc[r][c] = 0.0f;

#pragma unroll 2
        for (int k = 0; k < 64; k += 4) {
            float wsl[4][8];
#pragma unroll
            for (int kk = 0; kk < 4; ++kk) {
                float4 lo = *(const float4*)&wsh[(k + kk) * CMID + d0];
                float4 hi = *(const float4*)&wsh[(k + kk) * CMID + 128 + d0];
                wsl[kk][0] = lo.x; wsl[kk][1] = lo.y; wsl[kk][2] = lo.z; wsl[kk][3] = lo.w;
                wsl[kk][4] = hi.x; wsl[kk][5] = hi.y; wsl[kk][6] = hi.z; wsl[kk][7] = hi.w;
            }
#pragma unroll
            for (int r = 0; r < 8; ++r) {
                float4 xv = *(const float4*)&xs[(mbase + r) * CIN + k];
                float xk[4] = {xv.x, xv.y, xv.z, xv.w};
#pragma unroll
                for (int kk = 0; kk < 4; ++kk)
#pragma unroll
                    for (int c = 0; c < 8; ++c)
                        acc[r][c] = fmaf(xk[kk], wsl[kk][c], acc[r][c]);
            }
        }
#pragma unroll
        for (int r = 0; r < 8; ++r)
#pragma unroll
            for (int c = 0; c < 8; ++c)
                vmax[c] = fmaxf(vmax[c], acc[r][c]);
    }

    // cross-mg max reduction via LDS
#pragma unroll
    for (int c = 0; c < 4; ++c) {
        red[mg * 256 + d0 + c]       = vmax[c];
        red[mg * 256 + 128 + d0 + c] = vmax[4 + c];
    }
    __syncthreads();
    {
        float zm = red[tid];
#pragma unroll
        for (int g = 1; g < 8; ++g) zm = fmaxf(zm, red[g * 256 + tid]);
        zv[tid] = zm + b1[tid];   // bias commutes with max over m
    }
    __syncthreads();

    // ---- restage wsh <- w2xt (phase-1 reads done) ----
    {
        const float4* wg4 = (const float4*)(ws + W2XT_OFF);
        float4* wt4 = (float4*)wsh;
#pragma unroll
        for (int i = 0; i < 16; ++i) wt4[tid + 256 * i] = wg4[tid + 256 * i];
    }

    // ---- v[j] = sum_d zv[d] * w2zt[d][j]  (K=256, split over 4 d-parts) ----
    {
        const int jq = tid & 63;      // j quad: j = 4*jq..4*jq+3
        const int dpart = tid >> 6;   // d range [64*dpart, 64*dpart+64)
        const float4* w2zt4 = (const float4*)(ws + W2ZT_OFF);
        float4 vacc = make_float4(0.f, 0.f, 0.f, 0.f);
#pragma unroll 4
        for (int d = 0; d < 64; ++d) {
            int dd = dpart * 64 + d;
            float s = zv[dd];                    // LDS broadcast
            float4 wv = w2zt4[dd * 64 + jq];     // coalesced from L2
            vacc.x = fmaf(s, wv.x, vacc.x);
            vacc.y = fmaf(s, wv.y, vacc.y);
            vacc.z = fmaf(s, wv.z, vacc.z);
            vacc.w = fmaf(s, wv.w, vacc.w);
        }
        ((float4*)red)[dpart * 64 + jq] = vacc;
    }
    __syncthreads();
    vv[tid] = red[tid] + red[256 + tid] + red[512 + tid] + red[768 + tid];
    __syncthreads();

    // =================== phase 2: out = x@w2x^T + v ===================
    const float4 vlo = *(const float4*)&vv[d0];
    const float4 vhi = *(const float4*)&vv[128 + d0];
    float* __restrict__ og = out + (size_t)bn * (MM * COUT);

    for (int chunk = 0; chunk < 4; ++chunk) {
        const int mbase = chunk * 64 + mg * 8;
        float acc[8][8];
#pragma unroll
        for (int r = 0; r < 8; ++r)
#pragma unroll
            for (int c = 0; c < 8; ++c) acc[r][c] = 0.0f;

#pragma unroll 2
        for (int k = 0; k < 64; k += 4) {
            float wsl[4][8];
#pragma unroll
            for (int kk = 0; kk < 4; ++kk) {
                float4 lo = *(const float4*)&wsh[(k + kk) * CMID + d0];
                float4 hi = *(const float4*)&wsh[(k + kk) * CMID + 128 + d0];
                wsl[kk][0] = lo.x; wsl[kk][1] = lo.y; wsl[kk][2] = lo.z; wsl[kk][3] = lo.w;
                wsl[kk][4] = hi.x; wsl[kk][5] = hi.y; wsl[kk][6] = hi.z; wsl[kk][7] = hi.w;
            }
#pragma unroll
            for (int r = 0; r < 8; ++r) {
                float4 xv = *(const float4*)&xs[(mbase + r) * CIN + k];
                float xk[4] = {xv.x, xv.y, xv.z, xv.w};
#pragma unroll
                for (int kk = 0; kk < 4; ++kk)
#pragma unroll
                    for (int c = 0; c < 8; ++c)
                        acc[r][c] = fmaf(xk[kk], wsl[kk][c], acc[r][c]);
            }
        }

        // epilogue: add broadcast v, float4 stores (coalesced across dg lanes)
#pragma unroll
        for (int r = 0; r < 8; ++r) {
            const int m = mbase + r;
            float4 o0, o1;
            o0.x = acc[r][0] + vlo.x; o0.y = acc[r][1] + vlo.y;
            o0.z = acc[r][2] + vlo.z; o0.w = acc[r][3] + vlo.w;
            o1.x = acc[r][4] + vhi.x; o1.y = acc[r][5] + vhi.y;
            o1.z = acc[r][6] + vhi.z; o1.w = acc[r][7] + vhi.w;
            *(float4*)&og[m * COUT + d0]       = o0;
            *(float4*)&og[m * COUT + 128 + d0] = o1;
        }
    }
}

extern "C" void kernel_launch(void* const* d_in, const int* in_sizes, int n_in,
                              void* d_out, int out_size, void* d_ws, size_t ws_size,
                              hipStream_t stream) {
    const float* x  = (const float*)d_in[0];
    const float* w1 = (const float*)d_in[1];
    const float* b1 = (const float*)d_in[2];
    const float* w2 = (const float*)d_in[3];
    float* ws  = (float*)d_ws;
    float* out = (float*)d_out;

    hipLaunchKernelGGL(prep_transpose, dim3(384), dim3(256), 0, stream, w1, w2, ws);
    hipLaunchKernelGGL(fused_pointnet, dim3(2048), dim3(256), 0, stream, x, b1, ws, out);
}

// Round 2
// 639.935 us; speedup vs baseline: 1.5047x; 1.5047x over previous
//
#include <hip/hip_runtime.h>

// SetEncoderPointNet fused kernel — bf16x2 split-precision MFMA version.
//
// Shapes: x (8,256,256,64) f32; w1 (256,64); b1 (256); w2 (256,320); out (8,256,256,256).
// Restructure: out = x @ w2[:, :64]^T + v,  v[bn] = (max_m(x@w1^T) + b1) @ w2[:, 64:]^T.
// One block per (b,n): A-frags (x) loaded global->reg once, split to bf16 hi/lo, reused
// in both GEMM phases. Weights staged in LDS as bf16 hi/lo planes [d][72] (k-padded).
// Each fp32 product a*b ~= ahi*bhi + ahi*blo + alo*bhi (3 MFMA passes, fp32-class accuracy).

#define CIN  64
#define KPAD 72            // padded k-stride in LDS (16B-aligned rows, breaks pow2 banks)
#define PLANE 18432        // 256 * 72 shorts per LDS plane

typedef __attribute__((ext_vector_type(8))) short short8;
typedef __attribute__((ext_vector_type(4))) float float4v;

__device__ __forceinline__ short f2bf(float f) {
    union { float f; unsigned u; } c; c.f = f;
    unsigned u = c.u;
    unsigned r = (u + 0x7FFFu + ((u >> 16) & 1u)) >> 16;  // round-to-nearest-even
    return (short)r;
}
__device__ __forceinline__ float bf2f(short s) {
    union { unsigned u; float f; } c;
    c.u = ((unsigned)(unsigned short)s) << 16;
    return c.f;
}

// ---- prep: split weights to bf16 hi/lo planes, transpose w2z ----
// ws layout (bytes): [0: w1 hi 32K | 32K: w1 lo 32K | 64K: w2x hi 32K | 96K: w2x lo 32K |
//                     128K: w2zt fp32 256x256 = 256K]   total 384 KB
__global__ void prep_weights(const float* __restrict__ w1,
                             const float* __restrict__ w2,
                             short* __restrict__ wsS) {
    int i = blockIdx.x * 256 + threadIdx.x;
    if (i < 16384) {                       // w1 [d][k] row-major, used as-is
        float f = w1[i];
        short h = f2bf(f);
        wsS[i] = h;
        wsS[16384 + i] = f2bf(f - bf2f(h));
    } else if (i < 32768) {                // w2x: first 64 cols of w2 rows
        int q = i - 16384;
        int j = q >> 6, k = q & 63;
        float f = w2[j * 320 + k];
        short h = f2bf(f);
        wsS[32768 + q] = h;
        wsS[49152 + q] = f2bf(f - bf2f(h));
    } else if (i < 98304) {                // w2zt[d][j] = w2[j][64+d], fp32
        int q = i - 32768;
        int d = q >> 8, j = q & 255;
        ((float*)(wsS + 65536))[q] = w2[j * 320 + 64 + d];
    }
}

// LDS: 73728 (w planes) + 4096 (red) + 1024 (zv) + 1024 (vv) = 79872 B -> 2 blocks/CU.
__global__ __launch_bounds__(256, 2)
void fused_pointnet(const float* __restrict__ x,
                    const float* __restrict__ b1,
                    const short* __restrict__ w1p,
                    const short* __restrict__ w2xp,
                    const float* __restrict__ w2zt,
                    float* __restrict__ out) {
    __shared__ short wlds[2 * PLANE];   // hi plane @0, lo plane @PLANE
    __shared__ float red[1024];         // cross-wave scratch (max-reduce / v partials)
    __shared__ float zv[256];
    __shared__ float vv[256];

    const int tid = threadIdx.x;
    const int bn  = blockIdx.x;
    const int w   = tid >> 6;           // wave id 0..3 -> m rows [64w, 64w+64)
    const int l   = tid & 63;
    const int dl  = l & 15;             // MFMA col lane
    const int q   = l >> 4;             // MFMA quad
    const int mw  = w * 64;
    const float* __restrict__ xg = x + (size_t)bn * (256 * CIN);

    // ---- A-frag global loads: xa[t][s] = x[mw+t*16+dl][s*32+q*8 .. +7] ----
    float4 xa0[4][2], xa1[4][2];
#pragma unroll
    for (int t = 0; t < 4; ++t)
#pragma unroll
        for (int s = 0; s < 2; ++s) {
            const float* p = xg + (mw + t * 16 + dl) * CIN + s * 32 + q * 8;
            xa0[t][s] = *(const float4*)p;
            xa1[t][s] = *(const float4*)(p + 4);
        }

    // ---- stage w1 hi/lo planes into LDS (pad k 64->72) ----
    {
        const short8* src = (const short8*)w1p;
#pragma unroll
        for (int it = 0; it < 16; ++it) {
            int i = tid + 256 * it;                 // i in [0,4096): 16B chunks
            int plane = i >> 11;                    // 2048 chunks per plane
            int c = i & 2047;
            int row = c >> 3, k = (c & 7) << 3;
            *(short8*)&wlds[plane * PLANE + row * KPAD + k] = src[i];
        }
    }

    // ---- convert A frags to bf16 hi/lo ----
    short8 ahi[4][2], alo[4][2];
#pragma unroll
    for (int t = 0; t < 4; ++t)
#pragma unroll
        for (int s = 0; s < 2; ++s) {
            float e[8];
            e[0] = xa0[t][s].x; e[1] = xa0[t][s].y; e[2] = xa0[t][s].z; e[3] = xa0[t][s].w;
            e[4] = xa1[t][s].x; e[5] = xa1[t][s].y; e[6] = xa1[t][s].z; e[7] = xa1[t][s].w;
#pragma unroll
            for (int j = 0; j < 8; ++j) {
                short h = f2bf(e[j]);
                ahi[t][s][j] = h;
                alo[t][s][j] = f2bf(e[j] - bf2f(h));
            }
        }
    __syncthreads();

    // =================== phase 1: z = x@w1^T, max over m ===================
#pragma unroll
    for (int chunk = 0; chunk < 4; ++chunk) {
        const int d0c = chunk * 64;
        short8 bhi[4][2], blo[4][2];
#pragma unroll
        for (int dt = 0; dt < 4; ++dt)
#pragma unroll
            for (int s = 0; s < 2; ++s) {
                int off = (d0c + dt * 16 + dl) * KPAD + s * 32 + q * 8;
                bhi[dt][s] = *(const short8*)&wlds[off];
                blo[dt][s] = *(const short8*)&wlds[off + PLANE];
            }
        float4v acc[4][4];
#pragma unroll
        for (int t = 0; t < 4; ++t)
#pragma unroll
            for (int dt = 0; dt < 4; ++dt) {
                float4v a = {0.f, 0.f, 0.f, 0.f};
#pragma unroll
                for (int s = 0; s < 2; ++s) {
                    a = __builtin_amdgcn_mfma_f32_16x16x32_bf16(ahi[t][s], bhi[dt][s], a, 0, 0, 0);
                    a = __builtin_amdgcn_mfma_f32_16x16x32_bf16(ahi[t][s], blo[dt][s], a, 0, 0, 0);
                    a = __builtin_amdgcn_mfma_f32_16x16x32_bf16(alo[t][s], bhi[dt][s], a, 0, 0, 0);
                }
                acc[t][dt] = a;
            }
        // max over the wave's 64 m rows for each d col
#pragma unroll
        for (int dt = 0; dt < 4; ++dt) {
            float mx = -3.0e38f;
#pragma unroll
            for (int t = 0; t < 4; ++t)
#pragma unroll
                for (int r = 0; r < 4; ++r) mx = fmaxf(mx, acc[t][dt][r]);
            mx = fmaxf(mx, __shfl_xor(mx, 16));
            mx = fmaxf(mx, __shfl_xor(mx, 32));
            if (q == 0) red[w * 256 + d0c + dt * 16 + dl] = mx;
        }
    }
    __syncthreads();
    zv[tid] = fmaxf(fmaxf(red[tid], red[256 + tid]),
                    fmaxf(red[512 + tid], red[768 + tid])) + b1[tid];
    __syncthreads();

    // ---- restage w2x planes; v[j] = zv . w2zt[:,j] in fp32 ----
    {
        const short8* src = (const short8*)w2xp;
#pragma unroll
        for (int it = 0; it < 16; ++it) {
            int i = tid + 256 * it;
            int plane = i >> 11;
            int c = i & 2047;
            int row = c >> 3, k = (c & 7) << 3;
            *(short8*)&wlds[plane * PLANE + row * KPAD + k] = src[i];
        }
    }
    {
        const int jq = tid & 63;       // j quad
        const int dpart = tid >> 6;    // d range [64*dpart, +64)
        const float4* wz4 = (const float4*)w2zt;
        float4 vacc = make_float4(0.f, 0.f, 0.f, 0.f);
#pragma unroll 4
        for (int d = 0; d < 64; ++d) {
            int dd = dpart * 64 + d;
            float s = zv[dd];
            float4 wv = wz4[dd * 64 + jq];
            vacc.x = fmaf(s, wv.x, vacc.x);
            vacc.y = fmaf(s, wv.y, vacc.y);
            vacc.z = fmaf(s, wv.z, vacc.z);
            vacc.w = fmaf(s, wv.w, vacc.w);
        }
        ((float4*)red)[dpart * 64 + jq] = vacc;
    }
    __syncthreads();
    vv[tid] = red[tid] + red[256 + tid] + red[512 + tid] + red[768 + tid];
    __syncthreads();

    // =================== phase 2: out = x@w2x^T + v ===================
    float* __restrict__ og = out + (size_t)bn * (256 * 256);
#pragma unroll
    for (int chunk = 0; chunk < 4; ++chunk) {
        const int d0c = chunk * 64;
        short8 bhi[4][2], blo[4][2];
#pragma unroll
        for (int dt = 0; dt < 4; ++dt)
#pragma unroll
            for (int s = 0; s < 2; ++s) {
                int off = (d0c + dt * 16 + dl) * KPAD + s * 32 + q * 8;
                bhi[dt][s] = *(const short8*)&wlds[off];
                blo[dt][s] = *(const short8*)&wlds[off + PLANE];
            }
        float vdt[4];
#pragma unroll
        for (int dt = 0; dt < 4; ++dt) vdt[dt] = vv[d0c + dt * 16 + dl];
#pragma unroll
        for (int t = 0; t < 4; ++t)
#pragma unroll
            for (int dt = 0; dt < 4; ++dt) {
                float4v a = {0.f, 0.f, 0.f, 0.f};
#pragma unroll
                for (int s = 0; s < 2; ++s) {
                    a = __builtin_amdgcn_mfma_f32_16x16x32_bf16(ahi[t][s], bhi[dt][s], a, 0, 0, 0);
                    a = __builtin_amdgcn_mfma_f32_16x16x32_bf16(ahi[t][s], blo[dt][s], a, 0, 0, 0);
                    a = __builtin_amdgcn_mfma_f32_16x16x32_bf16(alo[t][s], bhi[dt][s], a, 0, 0, 0);
                }
                const int rowb = (mw + t * 16 + q * 4) * 256 + d0c + dt * 16 + dl;
#pragma unroll
                for (int r = 0; r < 4; ++r)
                    og[rowb + r * 256] = a[r] + vdt[dt];
            }
    }
}

extern "C" void kernel_launch(void* const* d_in, const int* in_sizes, int n_in,
                              void* d_out, int out_size, void* d_ws, size_t ws_size,
                              hipStream_t stream) {
    const float* x  = (const float*)d_in[0];
    const float* w1 = (const float*)d_in[1];
    const float* b1 = (const float*)d_in[2];
    const float* w2 = (const float*)d_in[3];
    short* wsS = (short*)d_ws;
    float* out = (float*)d_out;

    hipLaunchKernelGGL(prep_weights, dim3(384), dim3(256), 0, stream, w1, w2, wsS);
    hipLaunchKernelGGL(fused_pointnet, dim3(2048), dim3(256), 0, stream,
                       x, b1, wsS, wsS + 32768, (const float*)(wsS + 65536), out);
}